// Round 6
// baseline (161.415 us; speedup 1.0000x reference)
//
#include <hip/hip_runtime.h>
#include <hip/hip_bf16.h>
#include <math.h>

// Problem constants
#define BATCH 1024
#define X_DIM 32
#define U_DIM 8
#define PHI 128
#define HID 128

typedef float f4 __attribute__((ext_vector_type(4)));

__device__ __forceinline__ float fast_tanh(float x) {
    return 1.0f - 2.0f / (__expf(2.0f * x) + 1.0f);
}

// wave-uniform broadcast read of another lane's register (VALU pipe, no LDS)
__device__ __forceinline__ float rl(float v, int lane) {
    return __uint_as_float((unsigned)__builtin_amdgcn_readlane((int)__float_as_uint(v), lane));
}

// ---------------------------------------------------------------------------
// Fused kernel, symmetry-aware ROW-PAIR triangle stream.
// One block per batch row b, 512 threads (8 waves); wave u streams the lower
// triangle of symmetric L[b,u] (128x128). Iteration i in 0..63 processes the
// prefix of row i AND the prefix of row m=127-i (33 float4 chunks total):
//   lanes 0..a   (a=i>>2): row i,  chunk c = l      (lane-static!)
//   lanes a+1..32:         row m,  chunk c = 32-l   (lane-static, reversed)
//   lanes 33..63: idle (zeroed operands, address clamped to lane 32's line)
// Lane-static chunk indices mean ALL phi/Q float4 operands are registers;
// wave-uniform row scalars phi[row],Q[row] come via v_readlane. Diagonal
// weights (1/0.5/0) affect only lanes a (fwd end, pattern by j=i&3) and a+1
// (mirror end) -> compile-time masks in the unrolled body. Zero in-loop LDS.
// Each 128B line of the triangle is touched by exactly one instruction.
//   mu[b,u] = sum over tri: w*L_rq*(Q_r phi_q + Q_q phi_r)   (w=0.5 on diag)
//   sf[b,u] = 1 + 2 * sum over tri: w*L_rq*phi_r*phi_q
// ---------------------------------------------------------------------------
__global__ __launch_bounds__(512, 4) void fused_kernel(
    const float* __restrict__ x,
    const float* __restrict__ Q,
    const float* __restrict__ L,
    const float* __restrict__ W1, const float* __restrict__ b1,
    const float* __restrict__ W2, const float* __restrict__ b2,
    const float* __restrict__ W3, const float* __restrict__ b3,
    const float* __restrict__ W4, const float* __restrict__ b4,
    const float* __restrict__ logSigEps,
    float* __restrict__ mu_out,   // 8192 = (B,U,1)
    float* __restrict__ sig_out)  // 65536 = (B,U,U)
{
    const int b = blockIdx.x;
    const int t = threadIdx.x;     // 0..511

    __shared__ float sx[X_DIM];
    __shared__ float h[HID];
    __shared__ alignas(16) float s_phi[PHI];
    __shared__ alignas(16) float s_Q[U_DIM * PHI];   // 4KB

    // preload Q (1024 floats) with all 512 threads, and x with the first 32
    {
        const float2* Qg = (const float2*)(Q + (size_t)b * (U_DIM * PHI));
        ((float2*)s_Q)[t] = Qg[t];
    }
    if (t < X_DIM) sx[t] = x[b * X_DIM + t];
    __syncthreads();

    // ---- Phase 1: MLP on threads 0..127 ----
    float acc;
    if (t < HID) {
        acc = b1[t];
#pragma unroll
        for (int k = 0; k < X_DIM; ++k) acc += sx[k] * W1[k * HID + t];
        h[t] = fast_tanh(acc);
    }
    __syncthreads();
    if (t < HID) {
        acc = b2[t];
#pragma unroll 8
        for (int k = 0; k < HID; ++k) acc += h[k] * W2[k * HID + t];
        acc = fast_tanh(acc);
    }
    __syncthreads();
    if (t < HID) h[t] = acc;
    __syncthreads();
    if (t < HID) {
        acc = b3[t];
#pragma unroll 8
        for (int k = 0; k < HID; ++k) acc += h[k] * W3[k * HID + t];
        acc = fast_tanh(acc);
    }
    __syncthreads();
    if (t < HID) h[t] = acc;
    __syncthreads();
    if (t < HID) {
        acc = b4[t];
#pragma unroll 8
        for (int k = 0; k < HID; ++k) acc += h[k] * W4[k * HID + t];
        s_phi[t] = acc;
    }
    __syncthreads();

    // ---- Phase 2: per-wave row-pair triangle stream, zero in-loop LDS ----
    const int u = t >> 6;          // wave id = tile id, 0..7
    const int l = t & 63;          // lane

    const float* __restrict__ Qu   = s_Q + u * PHI;
    const f4*    __restrict__ phi4 = (const f4*)s_phi;
    const f4*    __restrict__ q4   = (const f4*)Qu;

    // lane-static operand registers (one-time LDS reads)
    f4 phiF = phi4[l & 15];            // forward role: chunk c = l (l<=15)
    f4 qF   = q4[l & 15];
    const int mi = (32 - l) & 31;      // mirror role: chunk c = 32-l (1<=l<=32)
    f4 phiM = phi4[mi];
    f4 qM   = q4[mi];
    if (l < 1 || l > 32) {             // idle/never-mirror lanes: zero operands
        phiM.x = phiM.y = phiM.z = phiM.w = 0.0f;
        qM.x = qM.y = qM.z = qM.w = 0.0f;
    }
    const float phi_lo = s_phi[l];
    const float phi_hi = s_phi[64 + l];
    const float q_lo   = Qu[l];
    const float q_hi   = Qu[64 + l];

    const int l16 = l << 4;                                   // fwd byte offset in row
    const int M16 = (l >= 1 && l <= 32) ? ((32 - l) << 4) : 0; // mirror byte offset

    const char* __restrict__ Lb =
        (const char*)(L + ((size_t)(b * U_DIM + u)) * (PHI * PHI));

    float accm = 0.0f, accf = 0.0f;

#pragma unroll 4
    for (int a = 0; a < 16; ++a) {
        const bool fwd = (l <= a);         // group-constant lane role
        const bool isA = (l == a);         // forward diagonal lane
        const bool isB = (l == a + 1);     // mirror diagonal lane
        const f4 ph = fwd ? phiF : phiM;   // group-hoisted operand select
        const f4 qv = fwd ? qF   : qM;

#pragma unroll
        for (int j = 0; j < 4; ++j) {
            const int i = 4 * a + j;       // row index (fwd); mirror row = 127-i
            const int off = fwd ? (i * 512 + l16) : ((127 - i) * 512 + M16);
            f4 v = *(const f4*)(Lb + off);

            // diagonal masks (compile-time by j): fwd lane a: k<j ->1, k==j ->0.5;
            // mirror lane a+1: k<3-j ->1, k==3-j ->0.5, else 0
            const float F0 = (0 < j) ? 1.f : ((0 == j) ? 0.5f : 0.f);
            const float F1 = (1 < j) ? 1.f : ((1 == j) ? 0.5f : 0.f);
            const float F2 = (2 < j) ? 1.f : ((2 == j) ? 0.5f : 0.f);
            const float F3 = (3 < j) ? 1.f : ((3 == j) ? 0.5f : 0.f);
            const float M0 = (0 < 3 - j) ? 1.f : ((0 == 3 - j) ? 0.5f : 0.f);
            const float M1 = (1 < 3 - j) ? 1.f : ((1 == 3 - j) ? 0.5f : 0.f);
            const float M2 = (2 < 3 - j) ? 1.f : ((2 == 3 - j) ? 0.5f : 0.f);
            const float M3 = (3 < 3 - j) ? 1.f : ((3 == 3 - j) ? 0.5f : 0.f);

            f4 vw;
            vw.x = v.x * (isA ? F0 : (isB ? M0 : 1.0f));
            vw.y = v.y * (isA ? F1 : (isB ? M1 : 1.0f));
            vw.z = v.z * (isA ? F2 : (isB ? M2 : 1.0f));
            vw.w = v.w * (isA ? F3 : (isB ? M3 : 1.0f));

            const float d1 = vw.x * ph.x + vw.y * ph.y + vw.z * ph.z + vw.w * ph.w;
            const float d2 = vw.x * qv.x + vw.y * qv.y + vw.z * qv.z + vw.w * qv.w;

            // wave-uniform row scalars via readlane (VALU, no LDS pipe)
            const float sp = fwd ? rl(phi_lo, i) : rl(phi_hi, 63 - i);
            const float sq = fwd ? rl(q_lo, i)   : rl(q_hi, 63 - i);

            accm += sq * d1 + sp * d2;
            accf += sp * d1;
        }
    }

    // intra-wave butterfly reduction (64 lanes)
#pragma unroll
    for (int off = 1; off < 64; off <<= 1) {
        accm += __shfl_xor(accm, off);
        accf += __shfl_xor(accf, off);
    }

    const int bu = b * U_DIM + u;
    if (l == 0) mu_out[bu] = accm;
    if (l < U_DIM) {
        const float sf = 1.0f + 2.0f * accf;
        sig_out[(size_t)bu * U_DIM + l] = (l == u) ? __expf(logSigEps[u]) * sf : 0.0f;
    }
}

extern "C" void kernel_launch(void* const* d_in, const int* in_sizes, int n_in,
                              void* d_out, int out_size, void* d_ws, size_t ws_size,
                              hipStream_t stream)
{
    const float* x         = (const float*)d_in[0];
    const float* Q         = (const float*)d_in[1];
    const float* L         = (const float*)d_in[2];
    const float* W1        = (const float*)d_in[3];
    const float* b1        = (const float*)d_in[4];
    const float* W2        = (const float*)d_in[5];
    const float* b2        = (const float*)d_in[6];
    const float* W3        = (const float*)d_in[7];
    const float* b3        = (const float*)d_in[8];
    const float* W4        = (const float*)d_in[9];
    const float* b4        = (const float*)d_in[10];
    const float* logSigEps = (const float*)d_in[11];

    float* out     = (float*)d_out;
    float* mu_out  = out;                   // 8192
    float* sig_out = out + BATCH * U_DIM;   // 65536

    fused_kernel<<<BATCH, 512, 0, stream>>>(x, Q, L,
                                            W1, b1, W2, b2, W3, b3, W4, b4,
                                            logSigEps, mu_out, sig_out);
}

// Round 7
// 112.118 us; speedup vs baseline: 1.4397x; 1.4397x over previous
//
#include <hip/hip_runtime.h>
#include <hip/hip_bf16.h>
#include <math.h>

// Problem constants
#define BATCH 1024
#define X_DIM 32
#define U_DIM 8
#define PHI 128
#define HID 128

// packed triangle chunk count (16B chunks): 2112 = 33 * 64 for BOTH the
// lower-prefix and upper-suffix orientations.
#define NTASK 2112

typedef float f4 __attribute__((ext_vector_type(4)));

__device__ __forceinline__ float fast_tanh(float x) {
    return 1.0f - 2.0f / (__expf(2.0f * x) + 1.0f);
}

// ---------------------------------------------------------------------------
// Triangle accumulation core. offs[] (VGPR-resident, compile-time indexed)
// holds byte offsets (r<<9)|(c<<4) of this lane's 33 16B chunks. Weights:
//   LOWER (UP=false): q<r -> 1, q==r -> 0.5, q>r -> 0
//   UPPER (UP=true):  q>r -> 1, q==r -> 0.5, q<r -> 0     (q = 4c+k)
// Masks are compile-time selects on e = +-(4c - r + k). In-loop LDS: one
// ds_read_b64 (pq8: {phi_r, Q_r}) + two ds_read_b128 (pq48: {phi4[c],Q4[c]}).
// ---------------------------------------------------------------------------
template<bool UP>
__device__ __forceinline__ void tri_accum(
    const char* __restrict__ Lb, const int* offs,
    const float2* __restrict__ pq8u, const char* __restrict__ pq48u,
    float& accm, float& accf)
{
#pragma unroll
    for (int i = 0; i < 33; ++i) {
        const int off = offs[i];
        const f4 v = *(const f4*)(Lb + off);
        const int r = off >> 9;
        const int c = (off >> 4) & 31;
        const float2 pq = pq8u[r];            // {phi[r], Q[r]}
        const char* pb = pq48u + c * 48;
        const f4 ph = *(const f4*)pb;         // phi4[c]
        const f4 qv = *(const f4*)(pb + 16);  // Q4[c]
        const int d0 = 4 * c - r;
        float w0, w1, w2, w3;
        {
            const int e0 = UP ? -(d0 + 0) : (d0 + 0);
            const int e1 = UP ? -(d0 + 1) : (d0 + 1);
            const int e2 = UP ? -(d0 + 2) : (d0 + 2);
            const int e3 = UP ? -(d0 + 3) : (d0 + 3);
            w0 = (e0 < 0) ? 1.0f : ((e0 == 0) ? 0.5f : 0.0f);
            w1 = (e1 < 0) ? 1.0f : ((e1 == 0) ? 0.5f : 0.0f);
            w2 = (e2 < 0) ? 1.0f : ((e2 == 0) ? 0.5f : 0.0f);
            w3 = (e3 < 0) ? 1.0f : ((e3 == 0) ? 0.5f : 0.0f);
        }
        const float vx = v.x * w0, vy = v.y * w1, vz = v.z * w2, vw = v.w * w3;
        const float d1 = vx * ph.x + vy * ph.y + vz * ph.z + vw * ph.w;
        const float d2 = vx * qv.x + vy * qv.y + vz * qv.z + vw * qv.w;
        accm += pq.y * d1 + pq.x * d2;
        accf += pq.x * d1;
    }
}

// ---------------------------------------------------------------------------
// Fused kernel. One block per batch row b, 512 threads (8 waves); wave u
// handles the symmetric tile L[b,u]. Even waves stream the packed LOWER
// triangle (row prefixes), odd waves the packed UPPER triangle (row
// suffixes) — identical math by symmetry, and the combined DRAM line-position
// histogram across tiles is uniform (channel balance). Per-lane chunk
// offsets are precomputed into registers from u16 LDS tables, so the hot
// loop has NO LDS in the address path.
//   mu[b,u] = sum over tri: w*L_rq*(Q_r phi_q + Q_q phi_r)
//   sf[b,u] = 1 + 2 * sum over tri: w*L_rq*phi_r*phi_q
// ---------------------------------------------------------------------------
__global__ __launch_bounds__(512, 4) void fused_kernel(
    const float* __restrict__ x,
    const float* __restrict__ Q,
    const float* __restrict__ L,
    const float* __restrict__ W1, const float* __restrict__ b1,
    const float* __restrict__ W2, const float* __restrict__ b2,
    const float* __restrict__ W3, const float* __restrict__ b3,
    const float* __restrict__ W4, const float* __restrict__ b4,
    const float* __restrict__ logSigEps,
    float* __restrict__ mu_out,   // 8192 = (B,U,1)
    float* __restrict__ sig_out)  // 65536 = (B,U,U)
{
    const int b = blockIdx.x;
    const int t = threadIdx.x;     // 0..511

    __shared__ float sx[X_DIM];
    __shared__ float h[HID];
    __shared__ alignas(16) float s_phi[PHI];
    __shared__ alignas(16) float s_Q[U_DIM * PHI];        // 4KB
    __shared__ unsigned short s_tabL[NTASK];              // 4.125KB
    __shared__ unsigned short s_tabU[NTASK];              // 4.125KB
    __shared__ alignas(8)  float2 s_pq8[U_DIM * PHI];     // 8KB  {phi_r, Q_r}
    __shared__ alignas(16) char s_pq48[U_DIM * 32 * 48];  // 12KB {phi4[c],Q4[c]}

    // preload Q (1024 floats) with all 512 threads, and x with the first 32
    {
        const float2* Qg = (const float2*)(Q + (size_t)b * (U_DIM * PHI));
        ((float2*)s_Q)[t] = Qg[t];
    }
    if (t < X_DIM) sx[t] = x[b * X_DIM + t];

    // build both chunk tables (identical for all blocks, once per block).
    // lower: row r has chunks c=0..m (m=r>>2), base cumL(r) = r + tri(r)
    // upper: row r has chunks c=m..31,      base cumU(r) = 32r - tri(r)
    // tri(r) = 2m(m-1) + rem*m, rem = r&3
    if (t < 256) {
        const int r   = t & 127;
        const int m   = r >> 2;
        const int rem = r & 3;
        const int tri = 2 * m * (m - 1) + rem * m;
        if (t < 128) {
            const int base = r + tri;
            for (int c = 0; c <= m; ++c)
                s_tabL[base + c] = (unsigned short)((r << 9) | (c << 4));
        } else {
            const int base = 32 * r - tri;
            for (int c = m; c < 32; ++c)
                s_tabU[base + (c - m)] = (unsigned short)((r << 9) | (c << 4));
        }
    }
    __syncthreads();

    // ---- Phase 1: MLP on threads 0..127 ----
    float acc;
    if (t < HID) {
        acc = b1[t];
#pragma unroll
        for (int k = 0; k < X_DIM; ++k) acc += sx[k] * W1[k * HID + t];
        h[t] = fast_tanh(acc);
    }
    __syncthreads();
    if (t < HID) {
        acc = b2[t];
#pragma unroll 8
        for (int k = 0; k < HID; ++k) acc += h[k] * W2[k * HID + t];
        acc = fast_tanh(acc);
    }
    __syncthreads();
    if (t < HID) h[t] = acc;
    __syncthreads();
    if (t < HID) {
        acc = b3[t];
#pragma unroll 8
        for (int k = 0; k < HID; ++k) acc += h[k] * W3[k * HID + t];
        acc = fast_tanh(acc);
    }
    __syncthreads();
    if (t < HID) h[t] = acc;
    __syncthreads();
    if (t < HID) {
        acc = b4[t];
#pragma unroll 8
        for (int k = 0; k < HID; ++k) acc += h[k] * W4[k * HID + t];
        s_phi[t] = acc;
    }
    __syncthreads();

    // ---- build packed operand tables (needs s_phi + s_Q) ----
    for (int k = t; k < U_DIM * PHI; k += 512) {
        const int uu = k >> 7, rr = k & 127;
        float2 e; e.x = s_phi[rr]; e.y = s_Q[(uu << 7) + rr];
        s_pq8[k] = e;
    }
    if (t < 256) {
        const int uu = t >> 5, cc = t & 31;
        const f4 ph = ((const f4*)s_phi)[cc];
        const f4 qv = ((const f4*)(s_Q + (uu << 7)))[cc];
        char* dst = s_pq48 + (size_t)(uu * 32 + cc) * 48;
        *(f4*)dst = ph;
        *(f4*)(dst + 16) = qv;
    }
    __syncthreads();

    // ---- Phase 2: per-wave packed-triangle stream ----
    const int u = t >> 6;          // wave id = tile id, 0..7
    const int l = t & 63;          // lane
    const bool isUp = (u & 1);

    // hoist this lane's 33 chunk offsets into registers (address path is
    // then pure VALU; these 33 u16 reads happen once, conflict-free)
    const unsigned short* __restrict__ tab = isUp ? s_tabU : s_tabL;
    int offs[33];
#pragma unroll
    for (int i = 0; i < 33; ++i) offs[i] = tab[(i << 6) + l];

    const char* __restrict__ Lb =
        (const char*)(L + ((size_t)(b * U_DIM + u)) * (PHI * PHI));
    const float2* __restrict__ pq8u  = s_pq8 + (u << 7);
    const char*   __restrict__ pq48u = s_pq48 + u * (32 * 48);

    float accm = 0.0f, accf = 0.0f;
    if (isUp) tri_accum<true >(Lb, offs, pq8u, pq48u, accm, accf);
    else      tri_accum<false>(Lb, offs, pq8u, pq48u, accm, accf);

    // intra-wave butterfly reduction (64 lanes)
#pragma unroll
    for (int off = 1; off < 64; off <<= 1) {
        accm += __shfl_xor(accm, off);
        accf += __shfl_xor(accf, off);
    }

    const int bu = b * U_DIM + u;
    if (l == 0) mu_out[bu] = accm;
    if (l < U_DIM) {
        const float sf = 1.0f + 2.0f * accf;
        sig_out[(size_t)bu * U_DIM + l] = (l == u) ? __expf(logSigEps[u]) * sf : 0.0f;
    }
}

extern "C" void kernel_launch(void* const* d_in, const int* in_sizes, int n_in,
                              void* d_out, int out_size, void* d_ws, size_t ws_size,
                              hipStream_t stream)
{
    const float* x         = (const float*)d_in[0];
    const float* Q         = (const float*)d_in[1];
    const float* L         = (const float*)d_in[2];
    const float* W1        = (const float*)d_in[3];
    const float* b1        = (const float*)d_in[4];
    const float* W2        = (const float*)d_in[5];
    const float* b2        = (const float*)d_in[6];
    const float* W3        = (const float*)d_in[7];
    const float* b3        = (const float*)d_in[8];
    const float* W4        = (const float*)d_in[9];
    const float* b4        = (const float*)d_in[10];
    const float* logSigEps = (const float*)d_in[11];

    float* out     = (float*)d_out;
    float* mu_out  = out;                   // 8192
    float* sig_out = out + BATCH * U_DIM;   // 65536

    fused_kernel<<<BATCH, 512, 0, stream>>>(x, Q, L,
                                            W1, b1, W2, b2, W3, b3, W4, b4,
                                            logSigEps, mu_out, sig_out);
}

// Round 8
// 72.934 us; speedup vs baseline: 2.2132x; 1.5372x over previous
//
#include <hip/hip_runtime.h>
#include <hip/hip_bf16.h>
#include <math.h>

// Problem constants
#define BATCH 1024
#define X_DIM 32
#define U_DIM 8
#define PHI 128
#define HID 128

// number of float4 tasks in the padded lower triangle:
// sum_r ceil((r+1)/4) = 2112 = 33 * 64  (exactly 33 iters per 64-lane wave)
#define NTASK 2112

typedef float f4 __attribute__((ext_vector_type(4)));

__device__ __forceinline__ float fast_tanh(float x) {
    return 1.0f - 2.0f / (__expf(2.0f * x) + 1.0f);
}

// ---------------------------------------------------------------------------
// R3 structure (best: 77.6us) + ONE change: the per-iter offset-table read is
// rolling-prefetched 4 iterations ahead into registers, so the global load's
// address is register-resident long before issue (LDS latency no longer sits
// in the VMEM address path). Everything else identical to R3.
// ---------------------------------------------------------------------------
__global__ __launch_bounds__(512) void fused_kernel(
    const float* __restrict__ x,
    const float* __restrict__ Q,
    const float* __restrict__ L,
    const float* __restrict__ W1, const float* __restrict__ b1,
    const float* __restrict__ W2, const float* __restrict__ b2,
    const float* __restrict__ W3, const float* __restrict__ b3,
    const float* __restrict__ W4, const float* __restrict__ b4,
    const float* __restrict__ logSigEps,
    float* __restrict__ mu_out,   // 8192 = (B,U,1)
    float* __restrict__ sig_out)  // 65536 = (B,U,U)
{
    const int b = blockIdx.x;
    const int t = threadIdx.x;     // 0..511

    __shared__ float sx[X_DIM];
    __shared__ float h[HID];
    __shared__ alignas(16) float s_phi[PHI];
    __shared__ alignas(16) float s_Q[U_DIM * PHI];   // 4KB
    __shared__ unsigned int s_off[NTASK];            // 8.25KB: tau -> byte offset

    // preload Q (1024 floats) with all 512 threads, and x with the first 32
    {
        const float2* Qg = (const float2*)(Q + (size_t)b * (U_DIM * PHI));
        ((float2*)s_Q)[t] = Qg[t];
    }
    if (t < X_DIM) sx[t] = x[b * X_DIM + t];

    // build the tau -> (r,c) offset table (identical for every block, cheap)
    for (int tau = t; tau < NTASK; tau += 512) {
        int a = (int)((sqrtf(2.0f * (float)tau + 1.0f) - 1.0f) * 0.5f);
        while (2 * (a + 1) * (a + 2) <= tau) ++a;
        while (2 * a * (a + 1) > tau) --a;
        const int o = tau - 2 * a * (a + 1);
        const int d = a + 1;
        const int j = (o >= 2 * d) ? ((o >= 3 * d) ? 3 : 2) : ((o >= d) ? 1 : 0);
        const int c = o - j * d;
        const int r = 4 * a + j;
        s_off[tau] = (unsigned)((r << 9) | (c << 4));  // r*512 + c*16 bytes
    }
    __syncthreads();

    // ---- Phase 1: MLP on threads 0..127 ----
    float acc;
    if (t < HID) {
        acc = b1[t];
#pragma unroll
        for (int k = 0; k < X_DIM; ++k) acc += sx[k] * W1[k * HID + t];
        h[t] = fast_tanh(acc);
    }
    __syncthreads();
    if (t < HID) {
        acc = b2[t];
#pragma unroll 8
        for (int k = 0; k < HID; ++k) acc += h[k] * W2[k * HID + t];
        acc = fast_tanh(acc);
    }
    __syncthreads();
    if (t < HID) h[t] = acc;
    __syncthreads();
    if (t < HID) {
        acc = b3[t];
#pragma unroll 8
        for (int k = 0; k < HID; ++k) acc += h[k] * W3[k * HID + t];
        acc = fast_tanh(acc);
    }
    __syncthreads();
    if (t < HID) h[t] = acc;
    __syncthreads();
    if (t < HID) {
        acc = b4[t];
#pragma unroll 8
        for (int k = 0; k < HID; ++k) acc += h[k] * W4[k * HID + t];
        s_phi[t] = acc;
    }
    __syncthreads();

    // ---- Phase 2: per-wave lower-triangle stream ----
    const int u = t >> 6;          // wave id = u, 0..7
    const int l = t & 63;          // lane

    const char* __restrict__ Lbase =
        (const char*)(L + ((size_t)(b * U_DIM + u)) * (PHI * PHI));
    const float* __restrict__ Qu = s_Q + u * PHI;
    const f4* __restrict__ s_phi4 = (const f4*)s_phi;
    const f4* __restrict__ Qu4 = (const f4*)Qu;

    // rolling 4-deep prefetch of this lane's chunk offsets: the global-load
    // address is in a VGPR 4 iterations before use, hiding LDS latency.
    int offs[4];
#pragma unroll
    for (int k = 0; k < 4; ++k) offs[k] = (int)s_off[(k << 6) + l];

    float accm = 0.0f, accf = 0.0f;
#pragma unroll
    for (int i = 0; i < 33; ++i) {
        const int off = offs[i & 3];                       // static after unroll
        if (i + 4 < 33) offs[i & 3] = (int)s_off[((i + 4) << 6) + l];

        const f4 v = __builtin_nontemporal_load((const f4*)(Lbase + off));
        const int r = off >> 9;
        const int c = (off >> 4) & 31;
        const float phir = s_phi[r];
        const float Qr   = Qu[r];
        const f4 ph = s_phi4[c];
        const f4 Qv = Qu4[c];
        const int e = 4 * c - r;   // q - r = e + k

        // k = 0..3, weight: q<r -> 1, q==r -> 0.5, q>r -> 0 (padding)
        {
            const float w = (e + 0 < 0) ? 1.0f : ((e + 0 == 0) ? 0.5f : 0.0f);
            const float tv = w * v.x;
            accm += tv * (Qr * ph.x + Qv.x * phir);
            accf += tv * (phir * ph.x);
        }
        {
            const float w = (e + 1 < 0) ? 1.0f : ((e + 1 == 0) ? 0.5f : 0.0f);
            const float tv = w * v.y;
            accm += tv * (Qr * ph.y + Qv.y * phir);
            accf += tv * (phir * ph.y);
        }
        {
            const float w = (e + 2 < 0) ? 1.0f : ((e + 2 == 0) ? 0.5f : 0.0f);
            const float tv = w * v.z;
            accm += tv * (Qr * ph.z + Qv.z * phir);
            accf += tv * (phir * ph.z);
        }
        {
            const float w = (e + 3 < 0) ? 1.0f : ((e + 3 == 0) ? 0.5f : 0.0f);
            const float tv = w * v.w;
            accm += tv * (Qr * ph.w + Qv.w * phir);
            accf += tv * (phir * ph.w);
        }
    }

    // intra-wave butterfly reduction (64 lanes)
#pragma unroll
    for (int off = 1; off < 64; off <<= 1) {
        accm += __shfl_xor(accm, off);
        accf += __shfl_xor(accf, off);
    }

    const int bu = b * U_DIM + u;
    if (l == 0) mu_out[bu] = accm;
    if (l < U_DIM) {
        const float sf = 1.0f + 2.0f * accf;
        sig_out[(size_t)bu * U_DIM + l] = (l == u) ? __expf(logSigEps[u]) * sf : 0.0f;
    }
}

extern "C" void kernel_launch(void* const* d_in, const int* in_sizes, int n_in,
                              void* d_out, int out_size, void* d_ws, size_t ws_size,
                              hipStream_t stream)
{
    const float* x         = (const float*)d_in[0];
    const float* Q         = (const float*)d_in[1];
    const float* L         = (const float*)d_in[2];
    const float* W1        = (const float*)d_in[3];
    const float* b1        = (const float*)d_in[4];
    const float* W2        = (const float*)d_in[5];
    const float* b2        = (const float*)d_in[6];
    const float* W3        = (const float*)d_in[7];
    const float* b3        = (const float*)d_in[8];
    const float* W4        = (const float*)d_in[9];
    const float* b4        = (const float*)d_in[10];
    const float* logSigEps = (const float*)d_in[11];

    float* out     = (float*)d_out;
    float* mu_out  = out;                   // 8192
    float* sig_out = out + BATCH * U_DIM;   // 65536

    fused_kernel<<<BATCH, 512, 0, stream>>>(x, Q, L,
                                            W1, b1, W2, b2, W3, b3, W4, b4,
                                            logSigEps, mu_out, sig_out);
}

// Round 9
// 70.218 us; speedup vs baseline: 2.2988x; 1.0387x over previous
//
#include <hip/hip_runtime.h>
#include <hip/hip_bf16.h>
#include <math.h>

// Problem constants
#define BATCH 1024
#define X_DIM 32
#define U_DIM 8
#define PHI 128
#define HID 128

// packed triangle chunk count (16B chunks): 2112 = 33 * 64 for BOTH the
// lower-prefix and upper-suffix orientations.
#define NTASK 2112

typedef float f4 __attribute__((ext_vector_type(4)));

__device__ __forceinline__ float fast_tanh(float x) {
    return 1.0f - 2.0f / (__expf(2.0f * x) + 1.0f);
}

// ---------------------------------------------------------------------------
// R8 structure (best: 72.9us) + ONE change: odd waves stream the packed UPPER
// triangle of their (symmetric) tile instead of the lower. Identical math by
// bitwise symmetry (L = A A^T + diag). Purpose: the lower-prefix stream's
// fetched 128B lines are start-of-row biased (position histogram 128/96/64/32
// within each 512B row, repeated every tile); mixing orientations balances it
// to 160/160/160/160 — uniform load on any 512B-periodic HBM channel hash.
// Everything else (rolling 4-deep offset prefetch, NT loads, operand reads,
// accumulation, reduction) is R8 verbatim.
//   lower weights: q<r -> 1, q==r -> 0.5, q>r -> 0   (ek = 4c+k-r)
//   upper weights: q>r -> 1, q==r -> 0.5, q<r -> 0   (ek = r-4c-k)
// ---------------------------------------------------------------------------
__global__ __launch_bounds__(512) void fused_kernel(
    const float* __restrict__ x,
    const float* __restrict__ Q,
    const float* __restrict__ L,
    const float* __restrict__ W1, const float* __restrict__ b1,
    const float* __restrict__ W2, const float* __restrict__ b2,
    const float* __restrict__ W3, const float* __restrict__ b3,
    const float* __restrict__ W4, const float* __restrict__ b4,
    const float* __restrict__ logSigEps,
    float* __restrict__ mu_out,   // 8192 = (B,U,1)
    float* __restrict__ sig_out)  // 65536 = (B,U,U)
{
    const int b = blockIdx.x;
    const int t = threadIdx.x;     // 0..511

    __shared__ float sx[X_DIM];
    __shared__ float h[HID];
    __shared__ alignas(16) float s_phi[PHI];
    __shared__ alignas(16) float s_Q[U_DIM * PHI];   // 4KB
    __shared__ unsigned short s_tabL[NTASK];         // 4.125KB
    __shared__ unsigned short s_tabU[NTASK];         // 4.125KB

    // preload Q (1024 floats) with all 512 threads, and x with the first 32
    {
        const float2* Qg = (const float2*)(Q + (size_t)b * (U_DIM * PHI));
        ((float2*)s_Q)[t] = Qg[t];
    }
    if (t < X_DIM) sx[t] = x[b * X_DIM + t];

    // build both chunk tables (identical for all blocks; once per block).
    // lower: row r has chunks c=0..m (m=r>>2), base cumL(r) = r + tri(r)
    // upper: row r has chunks c=m..31,      base cumU(r) = 32r - tri(r)
    // tri(r) = 2m(m-1) + rem*m, rem = r&3
    if (t < 256) {
        const int r   = t & 127;
        const int m   = r >> 2;
        const int rem = r & 3;
        const int tri = 2 * m * (m - 1) + rem * m;
        if (t < 128) {
            const int base = r + tri;
            for (int c = 0; c <= m; ++c)
                s_tabL[base + c] = (unsigned short)((r << 9) | (c << 4));
        } else {
            const int base = 32 * r - tri;
            for (int c = m; c < 32; ++c)
                s_tabU[base + (c - m)] = (unsigned short)((r << 9) | (c << 4));
        }
    }
    __syncthreads();

    // ---- Phase 1: MLP on threads 0..127 ----
    float acc;
    if (t < HID) {
        acc = b1[t];
#pragma unroll
        for (int k = 0; k < X_DIM; ++k) acc += sx[k] * W1[k * HID + t];
        h[t] = fast_tanh(acc);
    }
    __syncthreads();
    if (t < HID) {
        acc = b2[t];
#pragma unroll 8
        for (int k = 0; k < HID; ++k) acc += h[k] * W2[k * HID + t];
        acc = fast_tanh(acc);
    }
    __syncthreads();
    if (t < HID) h[t] = acc;
    __syncthreads();
    if (t < HID) {
        acc = b3[t];
#pragma unroll 8
        for (int k = 0; k < HID; ++k) acc += h[k] * W3[k * HID + t];
        acc = fast_tanh(acc);
    }
    __syncthreads();
    if (t < HID) h[t] = acc;
    __syncthreads();
    if (t < HID) {
        acc = b4[t];
#pragma unroll 8
        for (int k = 0; k < HID; ++k) acc += h[k] * W4[k * HID + t];
        s_phi[t] = acc;
    }
    __syncthreads();

    // ---- Phase 2: per-wave packed-triangle stream ----
    const int u = t >> 6;          // wave id = tile id, 0..7
    const int l = t & 63;          // lane
    const bool isUp = (u & 1) != 0;
    const int  dk   = isUp ? -1 : 1;

    const unsigned short* __restrict__ tab = isUp ? s_tabU : s_tabL;

    const char* __restrict__ Lbase =
        (const char*)(L + ((size_t)(b * U_DIM + u)) * (PHI * PHI));
    const float* __restrict__ Qu = s_Q + u * PHI;
    const f4* __restrict__ s_phi4 = (const f4*)s_phi;
    const f4* __restrict__ Qu4 = (const f4*)Qu;

    // rolling 4-deep prefetch of this lane's chunk offsets: the global-load
    // address is in a VGPR 4 iterations before use, hiding LDS latency.
    int offs[4];
#pragma unroll
    for (int k = 0; k < 4; ++k) offs[k] = (int)tab[(k << 6) + l];

    float accm = 0.0f, accf = 0.0f;
#pragma unroll
    for (int i = 0; i < 33; ++i) {
        const int off = offs[i & 3];                       // static after unroll
        if (i + 4 < 33) offs[i & 3] = (int)tab[((i + 4) << 6) + l];

        const f4 v = __builtin_nontemporal_load((const f4*)(Lbase + off));
        const int r = off >> 9;
        const int c = (off >> 4) & 31;
        const float phir = s_phi[r];
        const float Qr   = Qu[r];
        const f4 ph = s_phi4[c];
        const f4 Qv = Qu4[c];
        // ek for k=0; advance by dk per element. weight: ek<0 ->1, ==0 ->0.5, >0 ->0
        int ek = isUp ? (r - 4 * c) : (4 * c - r);

        {
            const float w = (ek < 0) ? 1.0f : ((ek == 0) ? 0.5f : 0.0f);
            const float tv = w * v.x;
            accm += tv * (Qr * ph.x + Qv.x * phir);
            accf += tv * (phir * ph.x);
        }
        ek += dk;
        {
            const float w = (ek < 0) ? 1.0f : ((ek == 0) ? 0.5f : 0.0f);
            const float tv = w * v.y;
            accm += tv * (Qr * ph.y + Qv.y * phir);
            accf += tv * (phir * ph.y);
        }
        ek += dk;
        {
            const float w = (ek < 0) ? 1.0f : ((ek == 0) ? 0.5f : 0.0f);
            const float tv = w * v.z;
            accm += tv * (Qr * ph.z + Qv.z * phir);
            accf += tv * (phir * ph.z);
        }
        ek += dk;
        {
            const float w = (ek < 0) ? 1.0f : ((ek == 0) ? 0.5f : 0.0f);
            const float tv = w * v.w;
            accm += tv * (Qr * ph.w + Qv.w * phir);
            accf += tv * (phir * ph.w);
        }
    }

    // intra-wave butterfly reduction (64 lanes)
#pragma unroll
    for (int off = 1; off < 64; off <<= 1) {
        accm += __shfl_xor(accm, off);
        accf += __shfl_xor(accf, off);
    }

    const int bu = b * U_DIM + u;
    if (l == 0) mu_out[bu] = accm;
    if (l < U_DIM) {
        const float sf = 1.0f + 2.0f * accf;
        sig_out[(size_t)bu * U_DIM + l] = (l == u) ? __expf(logSigEps[u]) * sf : 0.0f;
    }
}

extern "C" void kernel_launch(void* const* d_in, const int* in_sizes, int n_in,
                              void* d_out, int out_size, void* d_ws, size_t ws_size,
                              hipStream_t stream)
{
    const float* x         = (const float*)d_in[0];
    const float* Q         = (const float*)d_in[1];
    const float* L         = (const float*)d_in[2];
    const float* W1        = (const float*)d_in[3];
    const float* b1        = (const float*)d_in[4];
    const float* W2        = (const float*)d_in[5];
    const float* b2        = (const float*)d_in[6];
    const float* W3        = (const float*)d_in[7];
    const float* b3        = (const float*)d_in[8];
    const float* W4        = (const float*)d_in[9];
    const float* b4        = (const float*)d_in[10];
    const float* logSigEps = (const float*)d_in[11];

    float* out     = (float*)d_out;
    float* mu_out  = out;                   // 8192
    float* sig_out = out + BATCH * U_DIM;   // 65536

    fused_kernel<<<BATCH, 512, 0, stream>>>(x, Q, L,
                                            W1, b1, W2, b2, W3, b3, W4, b4,
                                            logSigEps, mu_out, sig_out);
}